// Round 1
// baseline (856.598 us; speedup 1.0000x reference)
//
#include <hip/hip_runtime.h>
#include <math.h>

#define NFFT  16000   // = 128 * 125
#define NRROW 128     // radix-2 axis (stride NCCOL)
#define NCCOL 125     // radix-5 axis (contiguous)
#define DFEAT 2048
#define TPB   512

__device__ __forceinline__ float2 cmul(float2 a, float2 b) {
    return make_float2(a.x*b.x - a.y*b.y, a.x*b.y + a.y*b.x);
}
// e^{i*pi*a}
__device__ __forceinline__ float2 eipi(float a) {
    float s, c;
    sincospif(a, &s, &c);
    return make_float2(c, s);
}

// One block per batch row. LDS holds z[16000] complex.
// Forward: z = sk_img + i*sk_seq ; Z = FFT(z) (DIF, four-step 128x125)
// Square: W = Z^2  (elementwise, permutation-independent)
// Inverse: w = IFFT(W) (DIT, consumes DIF layout, natural-order output)
// out = Im(w) / (2N)
__global__ void __launch_bounds__(TPB)
mcb_fft_conv_kernel(const float* __restrict__ img, const float* __restrict__ seq,
                    const int* __restrict__ hvec, const float* __restrict__ svec,
                    float* __restrict__ out)
{
    extern __shared__ float2 buf[];
    const int tid = threadIdx.x;
    const int b   = blockIdx.x;

    // ---- zero + count-sketch scatter (img -> re, seq -> im)
    for (int p = tid; p < NFFT; p += TPB) buf[p] = make_float2(0.f, 0.f);
    __syncthreads();
    {
        const float* irow = img + (size_t)b * DFEAT;
        const float* qrow = seq + (size_t)b * DFEAT;
        for (int j = tid; j < DFEAT; j += TPB) {
            float sj = svec[j];
            int   hj = hvec[j];
            atomicAdd(&buf[hj].x, irow[j] * sj);
            atomicAdd(&buf[hj].y, qrow[j] * sj);
        }
    }
    __syncthreads();

    // ---- forward step 1: radix-2 DIF along row axis (stride NCCOL), 7 stages
    for (int ls = 6; ls >= 0; --ls) {
        const int   h  = 1 << ls;
        const float ih = 1.0f / (float)h;
        for (int idx = tid; idx < 64 * NCCOL; idx += TPB) {
            const int c  = idx % NCCOL;
            const int t  = idx / NCCOL;           // butterfly id within column
            const int j  = t & (h - 1);
            const int i0 = ((t >> ls) << (ls + 1)) + j;
            const int p0 = i0 * NCCOL + c;
            const int p1 = p0 + h * NCCOL;
            float2 a = buf[p0], d = buf[p1];
            float2 dif = make_float2(a.x - d.x, a.y - d.y);
            buf[p0] = make_float2(a.x + d.x, a.y + d.y);
            buf[p1] = cmul(dif, eipi(-(float)j * ih));   // w_{2h}^j
        }
        __syncthreads();
    }

    // ---- forward step 2: cross twiddle  *= exp(-2pi i * c * brev7(r) / N)
    for (int p = tid; p < NFFT; p += TPB) {
        const int r  = p / NCCOL;
        const int c  = p - r * NCCOL;
        const int k1 = __brev((unsigned)r) >> 25;         // true k1 at this row
        buf[p] = cmul(buf[p], eipi((float)(c * k1) * (-2.0f / (float)NFFT)));
    }
    __syncthreads();

    const float c1 = 0.30901699437494742f, c2 = -0.80901699437494745f;
    const float s1 = 0.95105651629515357f, s2 =  0.58778525229247314f;

    // ---- forward step 3: radix-5 DIF along columns (contiguous), L = 125,25,5
    for (int L = 125; L >= 5; L /= 5) {
        const int   m  = L / 5;
        const float tw = -2.0f / (float)L;
        for (int idx = tid; idx < NRROW * 25; idx += TPB) {
            const int r  = idx / 25;
            const int w  = idx - r * 25;
            const int b5 = w / m;
            const int j  = w - b5 * m;
            const int base = r * NCCOL + b5 * L + j;
            float2 e0 = buf[base];
            float2 e1 = buf[base + m];
            float2 e2 = buf[base + 2*m];
            float2 e3 = buf[base + 3*m];
            float2 e4 = buf[base + 4*m];
            float2 t1 = make_float2(e1.x+e4.x, e1.y+e4.y);
            float2 t2 = make_float2(e2.x+e3.x, e2.y+e3.y);
            float2 t3 = make_float2(e1.x-e4.x, e1.y-e4.y);
            float2 t4 = make_float2(e2.x-e3.x, e2.y-e3.y);
            float2 f0 = make_float2(e0.x+t1.x+t2.x, e0.y+t1.y+t2.y);
            float2 m1 = make_float2(e0.x + c1*t1.x + c2*t2.x, e0.y + c1*t1.y + c2*t2.y);
            float2 m2 = make_float2(e0.x + c2*t1.x + c1*t2.x, e0.y + c2*t1.y + c1*t2.y);
            float2 v1 = make_float2(s1*t3.x + s2*t4.x, s1*t3.y + s2*t4.y);
            float2 v2 = make_float2(s2*t3.x - s1*t4.x, s2*t3.y - s1*t4.y);
            float2 f1 = make_float2(m1.x + v1.y, m1.y - v1.x);  // m1 - i v1
            float2 f4 = make_float2(m1.x - v1.y, m1.y + v1.x);  // m1 + i v1
            float2 f2 = make_float2(m2.x + v2.y, m2.y - v2.x);  // m2 - i v2
            float2 f3 = make_float2(m2.x - v2.y, m2.y + v2.x);  // m2 + i v2
            buf[base]       = f0;
            buf[base + m]   = cmul(f1, eipi(tw * (float)(1*j)));
            buf[base + 2*m] = cmul(f2, eipi(tw * (float)(2*j)));
            buf[base + 3*m] = cmul(f3, eipi(tw * (float)(3*j)));
            buf[base + 4*m] = cmul(f4, eipi(tw * (float)(4*j)));
        }
        __syncthreads();
    }

    // ---- inverse: radix-5 DIT, L = 5,25,125 (pointwise Z^2 fused into L=5 load)
    for (int L = 5; L <= 125; L *= 5) {
        const int   m  = L / 5;
        const float tw = 2.0f / (float)L;
        for (int idx = tid; idx < NRROW * 25; idx += TPB) {
            const int r  = idx / 25;
            const int w  = idx - r * 25;
            const int b5 = w / m;
            const int j  = w - b5 * m;
            const int base = r * NCCOL + b5 * L + j;
            float2 g0 = buf[base];
            float2 g1 = buf[base + m];
            float2 g2 = buf[base + 2*m];
            float2 g3 = buf[base + 3*m];
            float2 g4 = buf[base + 4*m];
            if (L == 5) {   // first inverse stage: square the spectrum (j=0, twiddles=1)
                g0 = make_float2(g0.x*g0.x - g0.y*g0.y, 2.f*g0.x*g0.y);
                g1 = make_float2(g1.x*g1.x - g1.y*g1.y, 2.f*g1.x*g1.y);
                g2 = make_float2(g2.x*g2.x - g2.y*g2.y, 2.f*g2.x*g2.y);
                g3 = make_float2(g3.x*g3.x - g3.y*g3.y, 2.f*g3.x*g3.y);
                g4 = make_float2(g4.x*g4.x - g4.y*g4.y, 2.f*g4.x*g4.y);
            } else {        // DIT twiddle: w_L^{-jt}
                g1 = cmul(g1, eipi(tw * (float)(1*j)));
                g2 = cmul(g2, eipi(tw * (float)(2*j)));
                g3 = cmul(g3, eipi(tw * (float)(3*j)));
                g4 = cmul(g4, eipi(tw * (float)(4*j)));
            }
            float2 t1 = make_float2(g1.x+g4.x, g1.y+g4.y);
            float2 t2 = make_float2(g2.x+g3.x, g2.y+g3.y);
            float2 t3 = make_float2(g1.x-g4.x, g1.y-g4.y);
            float2 t4 = make_float2(g2.x-g3.x, g2.y-g3.y);
            float2 w0 = make_float2(g0.x+t1.x+t2.x, g0.y+t1.y+t2.y);
            float2 m1 = make_float2(g0.x + c1*t1.x + c2*t2.x, g0.y + c1*t1.y + c2*t2.y);
            float2 m2 = make_float2(g0.x + c2*t1.x + c1*t2.x, g0.y + c2*t1.y + c1*t2.y);
            float2 v1 = make_float2(s1*t3.x + s2*t4.x, s1*t3.y + s2*t4.y);
            float2 v2 = make_float2(s2*t3.x - s1*t4.x, s2*t3.y - s1*t4.y);
            float2 w1 = make_float2(m1.x - v1.y, m1.y + v1.x);  // m1 + i v1
            float2 w4 = make_float2(m1.x + v1.y, m1.y - v1.x);  // m1 - i v1
            float2 w2 = make_float2(m2.x - v2.y, m2.y + v2.x);  // m2 + i v2
            float2 w3 = make_float2(m2.x + v2.y, m2.y - v2.x);  // m2 - i v2
            buf[base]       = w0;
            buf[base + m]   = w1;
            buf[base + 2*m] = w2;
            buf[base + 3*m] = w3;
            buf[base + 4*m] = w4;
        }
        __syncthreads();
    }

    // ---- inverse cross twiddle: *= exp(+2pi i * c * brev7(r) / N)
    for (int p = tid; p < NFFT; p += TPB) {
        const int r  = p / NCCOL;
        const int c  = p - r * NCCOL;
        const int k1 = __brev((unsigned)r) >> 25;
        buf[p] = cmul(buf[p], eipi((float)(c * k1) * (2.0f / (float)NFFT)));
    }
    __syncthreads();

    // ---- inverse: radix-2 DIT along rows, 7 stages (natural-order output)
    for (int ls = 0; ls <= 6; ++ls) {
        const int   h  = 1 << ls;
        const float ih = 1.0f / (float)h;
        for (int idx = tid; idx < 64 * NCCOL; idx += TPB) {
            const int c  = idx % NCCOL;
            const int t  = idx / NCCOL;
            const int j  = t & (h - 1);
            const int i0 = ((t >> ls) << (ls + 1)) + j;
            const int p0 = i0 * NCCOL + c;
            const int p1 = p0 + h * NCCOL;
            float2 a = buf[p0];
            float2 d = cmul(buf[p1], eipi((float)j * ih));  // w_{2h}^{-j}
            buf[p0] = make_float2(a.x + d.x, a.y + d.y);
            buf[p1] = make_float2(a.x - d.x, a.y - d.y);
        }
        __syncthreads();
    }

    // ---- out[b,n] = Im(w[n]) / (2N)   (position n holds w[n] — natural order)
    const float scale = 1.0f / (2.0f * (float)NFFT);
    float* orow = out + (size_t)b * NFFT;
    for (int n = tid; n < NFFT; n += TPB) orow[n] = buf[n].y * scale;
}

extern "C" void kernel_launch(void* const* d_in, const int* in_sizes, int n_in,
                              void* d_out, int out_size, void* d_ws, size_t ws_size,
                              hipStream_t stream)
{
    const float* img  = (const float*)d_in[0];
    const float* seq  = (const float*)d_in[1];
    const int*   hvec = (const int*)d_in[2];
    const float* svec = (const float*)d_in[3];
    float* out = (float*)d_out;

    const int B = in_sizes[0] / DFEAT;   // 2048
    const size_t lds_bytes = (size_t)NFFT * sizeof(float2);  // 128000 B

    // opt-in to >64KB dynamic LDS (idempotent, not stream-ordered)
    hipFuncSetAttribute((const void*)mcb_fft_conv_kernel,
                        hipFuncAttributeMaxDynamicSharedMemorySize,
                        (int)lds_bytes);

    hipLaunchKernelGGL(mcb_fft_conv_kernel, dim3(B), dim3(TPB), lds_bytes, stream,
                       img, seq, hvec, svec, out);
}

// Round 2
// 573.047 us; speedup vs baseline: 1.4948x; 1.4948x over previous
//
#include <hip/hip_runtime.h>
#include <math.h>

#define NFFT  16000   // = 128 * 125
#define NRROW 128     // radix-2 axis (stride NCCOL)
#define NCCOL 125     // radix-5 axis (contiguous)
#define DFEAT 2048
#define TPB   512
#define R2OFF 16000   // LDS offset: 64-entry w_128^j LUT (forward sign)
#define R5OFF 16064   // LDS offset: 125-entry w_125^k LUT (forward sign)
#define LDSN  16189   // total float2 elements in LDS

__device__ __forceinline__ float2 cmul(float2 a, float2 b) {
    return make_float2(a.x*b.x - a.y*b.y, a.x*b.y + a.y*b.x);
}
__device__ __forceinline__ float2 cmulc(float2 a, float2 b) {   // a * conj(b)
    return make_float2(a.x*b.x + a.y*b.y, a.y*b.x - a.x*b.y);
}
// e^{i*pi*a}
__device__ __forceinline__ float2 eipi(float a) {
    float s, c;
    sincospif(a, &s, &c);
    return make_float2(c, s);
}

// Cross-twiddle LUT: Wc[p] = exp(-2*pi*i * c * brev7(r) / N), p = r*125 + c
__global__ void fill_cross_lut(float2* __restrict__ ws) {
    int p = blockIdx.x * 256 + threadIdx.x;
    if (p < NFFT) {
        int r  = p / NCCOL;
        int c  = p - r * NCCOL;
        int k1 = __brev((unsigned)r) >> 25;
        ws[p]  = eipi((float)(c * k1) * (-2.0f / (float)NFFT));
    }
}

// One block per batch row. LDS holds z[16000] complex + twiddle LUTs.
// Forward: z = sk_img + i*sk_seq ; Z = FFT(z) (DIF, four-step 128x125)
// Square: W = Z^2  (fused into first inverse radix-5 stage)
// Inverse: w = IFFT(W) (DIT, consumes DIF layout, natural-order output)
// out = Im(w) / (2N)  (fused into last inverse radix-2 stage)
__global__ void __launch_bounds__(TPB)
mcb_fft_conv_kernel(const float* __restrict__ img, const float* __restrict__ seq,
                    const int* __restrict__ hvec, const float* __restrict__ svec,
                    float* __restrict__ out, const float2* __restrict__ cross)
{
    extern __shared__ float2 buf[];
    const int tid = threadIdx.x;
    const int b   = blockIdx.x;

    // cross twiddle fetch (LUT if available, else compute)
    auto CW = [&](int p) -> float2 {
        if (cross) return cross[p];
        int r = p / NCCOL, c = p - r * NCCOL;
        int k1 = __brev((unsigned)r) >> 25;
        return eipi((float)(c * k1) * (-2.0f / (float)NFFT));
    };

    // ---- zero + build LDS twiddle LUTs
    for (int p = tid; p < NFFT; p += TPB) buf[p] = make_float2(0.f, 0.f);
    if (tid < 64) {
        buf[R2OFF + tid] = eipi(-(float)tid * (1.0f / 64.0f));       // w_128^j
    } else if (tid < 64 + 125) {
        int k = tid - 64;
        buf[R5OFF + k] = eipi((float)k * (-2.0f / 125.0f));          // w_125^k
    }
    __syncthreads();

    // ---- count-sketch scatter (img -> re, seq -> im)
    {
        const float* irow = img + (size_t)b * DFEAT;
        const float* qrow = seq + (size_t)b * DFEAT;
        for (int j = tid; j < DFEAT; j += TPB) {
            float sj = svec[j];
            int   hj = hvec[j];
            atomicAdd(&buf[hj].x, irow[j] * sj);
            atomicAdd(&buf[hj].y, qrow[j] * sj);
        }
    }
    __syncthreads();

    // ---- forward radix-2 DIF along row axis (stride NCCOL), stages ls=6..1
    for (int ls = 6; ls >= 1; --ls) {
        const int h  = 1 << ls;
        const int sh = 6 - ls;                     // LUT index = j << sh
        for (int idx = tid; idx < 64 * NCCOL; idx += TPB) {
            const int c  = idx % NCCOL;
            const int t  = idx / NCCOL;
            const int j  = t & (h - 1);
            const int i0 = ((t >> ls) << (ls + 1)) + j;
            const int p0 = i0 * NCCOL + c;
            const int p1 = p0 + h * NCCOL;
            float2 a = buf[p0], d = buf[p1];
            float2 dif = make_float2(a.x - d.x, a.y - d.y);
            float2 w   = buf[R2OFF + (j << sh)];
            buf[p0] = make_float2(a.x + d.x, a.y + d.y);
            buf[p1] = cmul(dif, w);
        }
        __syncthreads();
    }

    // ---- forward radix-2 stage ls=0 (twiddle=1) fused with cross twiddle
    for (int idx = tid; idx < 64 * NCCOL; idx += TPB) {
        const int c  = idx % NCCOL;
        const int t  = idx / NCCOL;
        const int p0 = (2 * t) * NCCOL + c;
        const int p1 = p0 + NCCOL;
        float2 a = buf[p0], d = buf[p1];
        float2 su = make_float2(a.x + d.x, a.y + d.y);
        float2 df = make_float2(a.x - d.x, a.y - d.y);
        buf[p0] = cmul(su, CW(p0));
        buf[p1] = cmul(df, CW(p1));
    }
    __syncthreads();

    const float c1 = 0.30901699437494742f, c2 = -0.80901699437494745f;
    const float s1 = 0.95105651629515357f, s2 =  0.58778525229247314f;

    // ---- forward radix-5 DIF along columns (contiguous), L = 125, 25, 5
    for (int L = 125; L >= 5; L /= 5) {
        const int m    = L / 5;
        const int mult = 125 / L;                  // w_L^k = R5[k*mult]
        for (int idx = tid; idx < NRROW * 25; idx += TPB) {
            const int r  = idx / 25;
            const int w  = idx - r * 25;
            const int b5 = w / m;
            const int j  = w - b5 * m;
            const int base = r * NCCOL + b5 * L + j;
            float2 e0 = buf[base];
            float2 e1 = buf[base + m];
            float2 e2 = buf[base + 2*m];
            float2 e3 = buf[base + 3*m];
            float2 e4 = buf[base + 4*m];
            float2 t1 = make_float2(e1.x+e4.x, e1.y+e4.y);
            float2 t2 = make_float2(e2.x+e3.x, e2.y+e3.y);
            float2 t3 = make_float2(e1.x-e4.x, e1.y-e4.y);
            float2 t4 = make_float2(e2.x-e3.x, e2.y-e3.y);
            float2 f0 = make_float2(e0.x+t1.x+t2.x, e0.y+t1.y+t2.y);
            float2 m1 = make_float2(e0.x + c1*t1.x + c2*t2.x, e0.y + c1*t1.y + c2*t2.y);
            float2 m2 = make_float2(e0.x + c2*t1.x + c1*t2.x, e0.y + c2*t1.y + c1*t2.y);
            float2 v1 = make_float2(s1*t3.x + s2*t4.x, s1*t3.y + s2*t4.y);
            float2 v2 = make_float2(s2*t3.x - s1*t4.x, s2*t3.y - s1*t4.y);
            float2 f1 = make_float2(m1.x + v1.y, m1.y - v1.x);  // m1 - i v1
            float2 f4 = make_float2(m1.x - v1.y, m1.y + v1.x);  // m1 + i v1
            float2 f2 = make_float2(m2.x + v2.y, m2.y - v2.x);  // m2 - i v2
            float2 f3 = make_float2(m2.x - v2.y, m2.y + v2.x);  // m2 + i v2
            buf[base] = f0;
            if (L > 5) {
                const int jj = j * mult;
                buf[base + m]   = cmul(f1, buf[R5OFF + jj]);
                buf[base + 2*m] = cmul(f2, buf[R5OFF + 2*jj]);
                buf[base + 3*m] = cmul(f3, buf[R5OFF + 3*jj]);
                buf[base + 4*m] = cmul(f4, buf[R5OFF + 4*jj]);
            } else {
                buf[base + m]   = f1;
                buf[base + 2*m] = f2;
                buf[base + 3*m] = f3;
                buf[base + 4*m] = f4;
            }
        }
        __syncthreads();
    }

    // ---- inverse radix-5 DIT, L = 5, 25, 125 (Z^2 fused into L=5 load)
    for (int L = 5; L <= 125; L *= 5) {
        const int m    = L / 5;
        const int mult = 125 / L;
        for (int idx = tid; idx < NRROW * 25; idx += TPB) {
            const int r  = idx / 25;
            const int w  = idx - r * 25;
            const int b5 = w / m;
            const int j  = w - b5 * m;
            const int base = r * NCCOL + b5 * L + j;
            float2 g0 = buf[base];
            float2 g1 = buf[base + m];
            float2 g2 = buf[base + 2*m];
            float2 g3 = buf[base + 3*m];
            float2 g4 = buf[base + 4*m];
            if (L == 5) {   // first inverse stage: square the spectrum (j=0, twiddles=1)
                g0 = make_float2(g0.x*g0.x - g0.y*g0.y, 2.f*g0.x*g0.y);
                g1 = make_float2(g1.x*g1.x - g1.y*g1.y, 2.f*g1.x*g1.y);
                g2 = make_float2(g2.x*g2.x - g2.y*g2.y, 2.f*g2.x*g2.y);
                g3 = make_float2(g3.x*g3.x - g3.y*g3.y, 2.f*g3.x*g3.y);
                g4 = make_float2(g4.x*g4.x - g4.y*g4.y, 2.f*g4.x*g4.y);
            } else {        // DIT twiddle: w_L^{-jt} = conj(R5[jt*mult])
                const int jj = j * mult;
                g1 = cmulc(g1, buf[R5OFF + jj]);
                g2 = cmulc(g2, buf[R5OFF + 2*jj]);
                g3 = cmulc(g3, buf[R5OFF + 3*jj]);
                g4 = cmulc(g4, buf[R5OFF + 4*jj]);
            }
            float2 t1 = make_float2(g1.x+g4.x, g1.y+g4.y);
            float2 t2 = make_float2(g2.x+g3.x, g2.y+g3.y);
            float2 t3 = make_float2(g1.x-g4.x, g1.y-g4.y);
            float2 t4 = make_float2(g2.x-g3.x, g2.y-g3.y);
            float2 w0 = make_float2(g0.x+t1.x+t2.x, g0.y+t1.y+t2.y);
            float2 m1 = make_float2(g0.x + c1*t1.x + c2*t2.x, g0.y + c1*t1.y + c2*t2.y);
            float2 m2 = make_float2(g0.x + c2*t1.x + c1*t2.x, g0.y + c2*t1.y + c1*t2.y);
            float2 v1 = make_float2(s1*t3.x + s2*t4.x, s1*t3.y + s2*t4.y);
            float2 v2 = make_float2(s2*t3.x - s1*t4.x, s2*t3.y - s1*t4.y);
            float2 w1 = make_float2(m1.x - v1.y, m1.y + v1.x);  // m1 + i v1
            float2 w4 = make_float2(m1.x + v1.y, m1.y - v1.x);  // m1 - i v1
            float2 w2 = make_float2(m2.x - v2.y, m2.y + v2.x);  // m2 + i v2
            float2 w3 = make_float2(m2.x + v2.y, m2.y - v2.x);  // m2 - i v2
            buf[base]       = w0;
            buf[base + m]   = w1;
            buf[base + 2*m] = w2;
            buf[base + 3*m] = w3;
            buf[base + 4*m] = w4;
        }
        __syncthreads();
    }

    // ---- inverse radix-2 stage ls=0 (twiddle=1) fused with conj cross twiddle
    for (int idx = tid; idx < 64 * NCCOL; idx += TPB) {
        const int c  = idx % NCCOL;
        const int t  = idx / NCCOL;
        const int p0 = (2 * t) * NCCOL + c;
        const int p1 = p0 + NCCOL;
        float2 a = cmulc(buf[p0], CW(p0));
        float2 d = cmulc(buf[p1], CW(p1));
        buf[p0] = make_float2(a.x + d.x, a.y + d.y);
        buf[p1] = make_float2(a.x - d.x, a.y - d.y);
    }
    __syncthreads();

    // ---- inverse radix-2 DIT along rows, stages ls=1..5
    for (int ls = 1; ls <= 5; ++ls) {
        const int h  = 1 << ls;
        const int sh = 6 - ls;
        for (int idx = tid; idx < 64 * NCCOL; idx += TPB) {
            const int c  = idx % NCCOL;
            const int t  = idx / NCCOL;
            const int j  = t & (h - 1);
            const int i0 = ((t >> ls) << (ls + 1)) + j;
            const int p0 = i0 * NCCOL + c;
            const int p1 = p0 + h * NCCOL;
            float2 a = buf[p0];
            float2 d = cmulc(buf[p1], buf[R2OFF + (j << sh)]);   // × w^{+j}
            buf[p0] = make_float2(a.x + d.x, a.y + d.y);
            buf[p1] = make_float2(a.x - d.x, a.y - d.y);
        }
        __syncthreads();
    }

    // ---- inverse radix-2 stage ls=6 fused with output write (natural order)
    const float scale = 1.0f / (2.0f * (float)NFFT);
    float* orow = out + (size_t)b * NFFT;
    for (int idx = tid; idx < 64 * NCCOL; idx += TPB) {
        const int c  = idx % NCCOL;
        const int t  = idx / NCCOL;                // j = t at this stage
        const int p0 = t * NCCOL + c;
        const int p1 = p0 + 64 * NCCOL;
        float2 a = buf[p0];
        float2 d = cmulc(buf[p1], buf[R2OFF + t]);
        orow[p0] = (a.y + d.y) * scale;
        orow[p1] = (a.y - d.y) * scale;
    }
}

extern "C" void kernel_launch(void* const* d_in, const int* in_sizes, int n_in,
                              void* d_out, int out_size, void* d_ws, size_t ws_size,
                              hipStream_t stream)
{
    const float* img  = (const float*)d_in[0];
    const float* seq  = (const float*)d_in[1];
    const int*   hvec = (const int*)d_in[2];
    const float* svec = (const float*)d_in[3];
    float* out = (float*)d_out;

    const int B = in_sizes[0] / DFEAT;   // 2048
    const size_t lds_bytes = (size_t)LDSN * sizeof(float2);  // 129512 B

    const bool use_lut = ws_size >= (size_t)NFFT * sizeof(float2);
    float2* cross = use_lut ? (float2*)d_ws : nullptr;
    if (use_lut) {
        hipLaunchKernelGGL(fill_cross_lut, dim3((NFFT + 255) / 256), dim3(256), 0, stream,
                           cross);
    }

    // opt-in to >64KB dynamic LDS (idempotent, not stream-ordered)
    hipFuncSetAttribute((const void*)mcb_fft_conv_kernel,
                        hipFuncAttributeMaxDynamicSharedMemorySize,
                        (int)lds_bytes);

    hipLaunchKernelGGL(mcb_fft_conv_kernel, dim3(B), dim3(TPB), lds_bytes, stream,
                       img, seq, hvec, svec, out, cross);
}

// Round 3
// 424.048 us; speedup vs baseline: 2.0201x; 1.3514x over previous
//
#include <hip/hip_runtime.h>
#include <math.h>

#define NFFT  16000   // = 128 * 125
#define NCCOL 125     // radix-5 axis (contiguous)
#define DFEAT 2048
#define TPB   512
#define R2OFF 16000   // LDS offset: 64-entry w_128^j LUT (forward sign)
#define R5OFF 16064   // LDS offset: 125-entry w_125^k LUT (forward sign)
#define LDSN  16189   // total float2 elements in LDS

__device__ __forceinline__ float2 cmul(float2 a, float2 b) {
    return make_float2(a.x*b.x - a.y*b.y, a.x*b.y + a.y*b.x);
}
__device__ __forceinline__ float2 cmulc(float2 a, float2 b) {   // a * conj(b)
    return make_float2(a.x*b.x + a.y*b.y, a.y*b.x - a.x*b.y);
}
__device__ __forceinline__ float2 cadd(float2 a, float2 b){ return make_float2(a.x+b.x, a.y+b.y); }
__device__ __forceinline__ float2 csub(float2 a, float2 b){ return make_float2(a.x-b.x, a.y-b.y); }
// e^{i*pi*a}
__device__ __forceinline__ float2 eipi(float a) {
    float s, c;
    sincospif(a, &s, &c);
    return make_float2(c, s);
}

#define C1f 0.30901699437494742f
#define C2f (-0.80901699437494745f)
#define S1f 0.95105651629515357f
#define S2f 0.58778525229247314f

// forward (DIF) radix-5 butterfly, in place, no twiddles
__device__ __forceinline__ void bfly5_fwd(float2& e0, float2& e1, float2& e2,
                                          float2& e3, float2& e4) {
    float2 t1 = cadd(e1, e4), t2 = cadd(e2, e3);
    float2 t3 = csub(e1, e4), t4 = csub(e2, e3);
    float2 f0 = make_float2(e0.x + t1.x + t2.x, e0.y + t1.y + t2.y);
    float2 m1 = make_float2(e0.x + C1f*t1.x + C2f*t2.x, e0.y + C1f*t1.y + C2f*t2.y);
    float2 m2 = make_float2(e0.x + C2f*t1.x + C1f*t2.x, e0.y + C2f*t1.y + C1f*t2.y);
    float2 v1 = make_float2(S1f*t3.x + S2f*t4.x, S1f*t3.y + S2f*t4.y);
    float2 v2 = make_float2(S2f*t3.x - S1f*t4.x, S2f*t3.y - S1f*t4.y);
    e0 = f0;
    e1 = make_float2(m1.x + v1.y, m1.y - v1.x);   // m1 - i v1
    e4 = make_float2(m1.x - v1.y, m1.y + v1.x);   // m1 + i v1
    e2 = make_float2(m2.x + v2.y, m2.y - v2.x);   // m2 - i v2
    e3 = make_float2(m2.x - v2.y, m2.y + v2.x);   // m2 + i v2
}
// inverse (DIT) radix-5 butterfly, in place, no twiddles
__device__ __forceinline__ void bfly5_inv(float2& e0, float2& e1, float2& e2,
                                          float2& e3, float2& e4) {
    float2 t1 = cadd(e1, e4), t2 = cadd(e2, e3);
    float2 t3 = csub(e1, e4), t4 = csub(e2, e3);
    float2 f0 = make_float2(e0.x + t1.x + t2.x, e0.y + t1.y + t2.y);
    float2 m1 = make_float2(e0.x + C1f*t1.x + C2f*t2.x, e0.y + C1f*t1.y + C2f*t2.y);
    float2 m2 = make_float2(e0.x + C2f*t1.x + C1f*t2.x, e0.y + C2f*t1.y + C1f*t2.y);
    float2 v1 = make_float2(S1f*t3.x + S2f*t4.x, S1f*t3.y + S2f*t4.y);
    float2 v2 = make_float2(S2f*t3.x - S1f*t4.x, S2f*t3.y - S1f*t4.y);
    e0 = f0;
    e1 = make_float2(m1.x - v1.y, m1.y + v1.x);   // m1 + i v1
    e4 = make_float2(m1.x + v1.y, m1.y - v1.x);   // m1 - i v1
    e2 = make_float2(m2.x - v2.y, m2.y + v2.x);   // m2 + i v2
    e3 = make_float2(m2.x + v2.y, m2.y - v2.x);   // m2 - i v2
}

// Cross-twiddle LUT: Wc[p] = exp(-2*pi*i * c * brev7(r) / N), p = r*125 + c
__global__ void fill_cross_lut(float2* __restrict__ ws) {
    int p = blockIdx.x * 256 + threadIdx.x;
    if (p < NFFT) {
        int r  = p / NCCOL;
        int c  = p - r * NCCOL;
        int k1 = __brev((unsigned)r) >> 25;
        ws[p]  = eipi((float)(c * k1) * (-2.0f / (float)NFFT));
    }
}

// One block per batch row. LDS holds z[16000] complex + twiddle LUTs.
// Forward: z = sk_img + i*sk_seq ; Z = FFT(z) (DIF four-step 128x125,
//          radix-8 + radix-16(+cross) on the 128 axis, radix-25 + radix-5 on 125)
// Square: W = Z^2  (fused into first inverse radix-5 stage)
// Inverse: mirror DIT, natural-order output; out = Im(w)/(2N) fused into last pass.
__global__ void __launch_bounds__(TPB)
mcb_fft_conv_kernel(const float* __restrict__ img, const float* __restrict__ seq,
                    const int* __restrict__ hvec, const float* __restrict__ svec,
                    float* __restrict__ out, const float2* __restrict__ cross)
{
    extern __shared__ float2 buf[];
    const int tid = threadIdx.x;
    const int b   = blockIdx.x;

    #define W2L(k) buf[R2OFF + (k)]
    #define R5L(k) buf[R5OFF + (k)]

    auto CW = [&](int p) -> float2 {
        if (cross) return cross[p];
        int r = p / NCCOL, c = p - r * NCCOL;
        int k1 = __brev((unsigned)r) >> 25;
        return eipi((float)(c * k1) * (-2.0f / (float)NFFT));
    };

    // ---- zero + build LDS twiddle LUTs
    for (int p = tid; p < NFFT; p += TPB) buf[p] = make_float2(0.f, 0.f);
    if (tid < 64) {
        W2L(tid) = eipi(-(float)tid * (1.0f / 64.0f));        // w_128^j
    } else if (tid < 64 + 125) {
        int k = tid - 64;
        R5L(k) = eipi((float)k * (-2.0f / 125.0f));           // w_125^k
    }
    __syncthreads();

    // ---- count-sketch scatter (img -> re, seq -> im)
    {
        const float* irow = img + (size_t)b * DFEAT;
        const float* qrow = seq + (size_t)b * DFEAT;
        for (int j = tid; j < DFEAT; j += TPB) {
            float sj = svec[j];
            int   hj = hvec[j];
            atomicAdd(&buf[hj].x, irow[j] * sj);
            atomicAdd(&buf[hj].y, qrow[j] * sj);
        }
    }
    __syncthreads();

    // ======== F1: forward radix-8, stages ls=6,5,4  (rows j + 16t) ========
    for (int idx = tid; idx < 16 * NCCOL; idx += TPB) {
        const int j = idx / NCCOL;          // 0..15
        const int c = idx - j * NCCOL;
        const int base = j * NCCOL + c;
        float2 x[8];
        #pragma unroll
        for (int t = 0; t < 8; ++t) x[t] = buf[base + 2000 * t];
        // ls=6 (dist 4): twiddle w128^{j+16t}
        #pragma unroll
        for (int t = 0; t < 4; ++t) {
            float2 u = x[t], v = x[t+4];
            x[t]   = cadd(u, v);
            x[t+4] = cmul(csub(u, v), W2L(j + 16*t));
        }
        // ls=5 (dist 2): twiddle w128^{2(j+16t)}, t=0,1
        #pragma unroll
        for (int q = 0; q < 8; q += 4)
            #pragma unroll
            for (int t = 0; t < 2; ++t) {
                float2 u = x[q+t], v = x[q+t+2];
                x[q+t]   = cadd(u, v);
                x[q+t+2] = cmul(csub(u, v), W2L(2*(j + 16*t)));
            }
        // ls=4 (dist 1): twiddle w128^{4j}
        {
            float2 w = W2L(4*j);
            #pragma unroll
            for (int q = 0; q < 8; q += 2) {
                float2 u = x[q], v = x[q+1];
                x[q]   = cadd(u, v);
                x[q+1] = cmul(csub(u, v), w);
            }
        }
        #pragma unroll
        for (int t = 0; t < 8; ++t) buf[base + 2000 * t] = x[t];
    }
    __syncthreads();

    // ======== F2: forward radix-16, stages ls=3..0 + cross twiddle (rows 16g+t) ====
    for (int idx = tid; idx < 8 * NCCOL; idx += TPB) {
        const int g = idx / NCCOL;          // 0..7
        const int c = idx - g * NCCOL;
        const int base = 2000 * g + c;
        float2 x[16];
        #pragma unroll
        for (int t = 0; t < 16; ++t) x[t] = buf[base + 125 * t];
        // ls=3 (dist 8): twiddle w128^{8t}
        #pragma unroll
        for (int t = 0; t < 8; ++t) {
            float2 u = x[t], v = x[t+8];
            x[t]   = cadd(u, v);
            x[t+8] = cmul(csub(u, v), W2L(8*t));
        }
        // ls=2 (dist 4): twiddle w128^{16t}, t=0..3
        #pragma unroll
        for (int q = 0; q < 16; q += 8)
            #pragma unroll
            for (int t = 0; t < 4; ++t) {
                float2 u = x[q+t], v = x[q+t+4];
                x[q+t]   = cadd(u, v);
                x[q+t+4] = cmul(csub(u, v), W2L(16*t));
            }
        // ls=1 (dist 2): twiddle w128^{32t}, t=0,1
        #pragma unroll
        for (int q = 0; q < 16; q += 4)
            #pragma unroll
            for (int t = 0; t < 2; ++t) {
                float2 u = x[q+t], v = x[q+t+2];
                x[q+t]   = cadd(u, v);
                x[q+t+2] = cmul(csub(u, v), W2L(32*t));
            }
        // ls=0 (dist 1): twiddle 1
        #pragma unroll
        for (int q = 0; q < 16; q += 2) {
            float2 u = x[q], v = x[q+1];
            x[q]   = cadd(u, v);
            x[q+1] = csub(u, v);
        }
        // cross twiddle (element at row 16g+t has flat index base + 125t)
        #pragma unroll
        for (int t = 0; t < 16; ++t)
            buf[base + 125 * t] = cmul(x[t], CW(base + 125 * t));
    }
    __syncthreads();

    // ======== F3: forward radix-25 (stages L=125, L=25) along columns ========
    for (int idx = tid; idx < 128 * 5; idx += TPB) {
        const int r  = idx / 5;
        const int j2 = idx - r * 5;
        const int base = r * NCCOL + j2;
        float2 x[25];
        #pragma unroll
        for (int q = 0; q < 25; ++q) x[q] = buf[base + 5 * q];
        // L=125: butterfly over t5 for each p, twiddle w125^{t*(j2+5p)}
        #pragma unroll
        for (int p = 0; p < 5; ++p) {
            bfly5_fwd(x[p], x[p+5], x[p+10], x[p+15], x[p+20]);
            const int jw = j2 + 5*p;
            x[p+5]  = cmul(x[p+5],  R5L(jw));
            x[p+10] = cmul(x[p+10], R5L(2*jw));
            x[p+15] = cmul(x[p+15], R5L(3*jw));
            x[p+20] = cmul(x[p+20], R5L(4*jw));
        }
        // L=25: butterfly over p for each t5, twiddle w25^{t*j2} = w125^{5t*j2}
        #pragma unroll
        for (int t5 = 0; t5 < 5; ++t5) {
            bfly5_fwd(x[5*t5], x[1+5*t5], x[2+5*t5], x[3+5*t5], x[4+5*t5]);
            x[1+5*t5] = cmul(x[1+5*t5], R5L(5*j2));
            x[2+5*t5] = cmul(x[2+5*t5], R5L(10*j2));
            x[3+5*t5] = cmul(x[3+5*t5], R5L(15*j2));
            x[4+5*t5] = cmul(x[4+5*t5], R5L(20*j2));
        }
        #pragma unroll
        for (int q = 0; q < 25; ++q) buf[base + 5 * q] = x[q];
    }
    __syncthreads();

    // ======== F4: forward radix-5, stage L=5 (contiguous, twiddles = 1) ========
    for (int idx = tid; idx < 128 * 25; idx += TPB) {
        const int r = idx / 25;
        const int q = idx - r * 25;
        const int base = r * NCCOL + 5 * q;
        float2 g0 = buf[base], g1 = buf[base+1], g2 = buf[base+2],
               g3 = buf[base+3], g4 = buf[base+4];
        bfly5_fwd(g0, g1, g2, g3, g4);
        buf[base] = g0; buf[base+1] = g1; buf[base+2] = g2;
        buf[base+3] = g3; buf[base+4] = g4;
    }
    __syncthreads();

    // ======== I1: spectrum square + inverse radix-5, stage L=5 ========
    for (int idx = tid; idx < 128 * 25; idx += TPB) {
        const int r = idx / 25;
        const int q = idx - r * 25;
        const int base = r * NCCOL + 5 * q;
        float2 g[5];
        #pragma unroll
        for (int t = 0; t < 5; ++t) {
            float2 z = buf[base + t];
            g[t] = make_float2(z.x*z.x - z.y*z.y, 2.f*z.x*z.y);   // Z^2
        }
        bfly5_inv(g[0], g[1], g[2], g[3], g[4]);
        #pragma unroll
        for (int t = 0; t < 5; ++t) buf[base + t] = g[t];
    }
    __syncthreads();

    // ======== I2: inverse radix-25 (stages L=25, L=125) ========
    for (int idx = tid; idx < 128 * 5; idx += TPB) {
        const int r  = idx / 5;
        const int j2 = idx - r * 5;
        const int base = r * NCCOL + j2;
        float2 x[25];
        #pragma unroll
        for (int q = 0; q < 25; ++q) x[q] = buf[base + 5 * q];
        // L=25 DIT: conj twiddle then inverse butterfly over p (per t5)
        #pragma unroll
        for (int t5 = 0; t5 < 5; ++t5) {
            x[1+5*t5] = cmulc(x[1+5*t5], R5L(5*j2));
            x[2+5*t5] = cmulc(x[2+5*t5], R5L(10*j2));
            x[3+5*t5] = cmulc(x[3+5*t5], R5L(15*j2));
            x[4+5*t5] = cmulc(x[4+5*t5], R5L(20*j2));
            bfly5_inv(x[5*t5], x[1+5*t5], x[2+5*t5], x[3+5*t5], x[4+5*t5]);
        }
        // L=125 DIT: conj twiddle then inverse butterfly over t5 (per p)
        #pragma unroll
        for (int p = 0; p < 5; ++p) {
            const int jw = j2 + 5*p;
            x[p+5]  = cmulc(x[p+5],  R5L(jw));
            x[p+10] = cmulc(x[p+10], R5L(2*jw));
            x[p+15] = cmulc(x[p+15], R5L(3*jw));
            x[p+20] = cmulc(x[p+20], R5L(4*jw));
            bfly5_inv(x[p], x[p+5], x[p+10], x[p+15], x[p+20]);
        }
        #pragma unroll
        for (int q = 0; q < 25; ++q) buf[base + 5 * q] = x[q];
    }
    __syncthreads();

    // ======== I3: inverse radix-16: conj cross + stages ls=0..3 (rows 16g+t) ====
    for (int idx = tid; idx < 8 * NCCOL; idx += TPB) {
        const int g = idx / NCCOL;
        const int c = idx - g * NCCOL;
        const int base = 2000 * g + c;
        float2 x[16];
        #pragma unroll
        for (int t = 0; t < 16; ++t)
            x[t] = cmulc(buf[base + 125 * t], CW(base + 125 * t));
        // ls=0 (dist 1): twiddle 1
        #pragma unroll
        for (int q = 0; q < 16; q += 2) {
            float2 u = x[q], v = x[q+1];
            x[q]   = cadd(u, v);
            x[q+1] = csub(u, v);
        }
        // ls=1 (dist 2): conj w128^{32t}
        #pragma unroll
        for (int q = 0; q < 16; q += 4)
            #pragma unroll
            for (int t = 0; t < 2; ++t) {
                float2 u = x[q+t];
                float2 v = cmulc(x[q+t+2], W2L(32*t));
                x[q+t]   = cadd(u, v);
                x[q+t+2] = csub(u, v);
            }
        // ls=2 (dist 4): conj w128^{16t}
        #pragma unroll
        for (int q = 0; q < 16; q += 8)
            #pragma unroll
            for (int t = 0; t < 4; ++t) {
                float2 u = x[q+t];
                float2 v = cmulc(x[q+t+4], W2L(16*t));
                x[q+t]   = cadd(u, v);
                x[q+t+4] = csub(u, v);
            }
        // ls=3 (dist 8): conj w128^{8t}
        #pragma unroll
        for (int t = 0; t < 8; ++t) {
            float2 u = x[t];
            float2 v = cmulc(x[t+8], W2L(8*t));
            x[t]   = cadd(u, v);
            x[t+8] = csub(u, v);
        }
        #pragma unroll
        for (int t = 0; t < 16; ++t) buf[base + 125 * t] = x[t];
    }
    __syncthreads();

    // ======== I4: inverse radix-8, stages ls=4,5,6 + output write (rows j+16t) ====
    const float scale = 1.0f / (2.0f * (float)NFFT);
    float* orow = out + (size_t)b * NFFT;
    for (int idx = tid; idx < 16 * NCCOL; idx += TPB) {
        const int j = idx / NCCOL;
        const int c = idx - j * NCCOL;
        const int base = j * NCCOL + c;
        float2 x[8];
        #pragma unroll
        for (int t = 0; t < 8; ++t) x[t] = buf[base + 2000 * t];
        // ls=4 (dist 1): conj w128^{4j}
        {
            float2 w = W2L(4*j);
            #pragma unroll
            for (int q = 0; q < 8; q += 2) {
                float2 u = x[q];
                float2 v = cmulc(x[q+1], w);
                x[q]   = cadd(u, v);
                x[q+1] = csub(u, v);
            }
        }
        // ls=5 (dist 2): conj w128^{2(j+16t)}, t=0,1
        #pragma unroll
        for (int q = 0; q < 8; q += 4)
            #pragma unroll
            for (int t = 0; t < 2; ++t) {
                float2 u = x[q+t];
                float2 v = cmulc(x[q+t+2], W2L(2*(j + 16*t)));
                x[q+t]   = cadd(u, v);
                x[q+t+2] = csub(u, v);
            }
        // ls=6 (dist 4): conj w128^{j+16t}, t=0..3 — then emit Im*scale
        #pragma unroll
        for (int t = 0; t < 4; ++t) {
            float2 u = x[t];
            float2 v = cmulc(x[t+4], W2L(j + 16*t));
            orow[base + 2000 * t]       = (u.y + v.y) * scale;
            orow[base + 2000 * (t + 4)] = (u.y - v.y) * scale;
        }
    }
}

extern "C" void kernel_launch(void* const* d_in, const int* in_sizes, int n_in,
                              void* d_out, int out_size, void* d_ws, size_t ws_size,
                              hipStream_t stream)
{
    const float* img  = (const float*)d_in[0];
    const float* seq  = (const float*)d_in[1];
    const int*   hvec = (const int*)d_in[2];
    const float* svec = (const float*)d_in[3];
    float* out = (float*)d_out;

    const int B = in_sizes[0] / DFEAT;   // 2048
    const size_t lds_bytes = (size_t)LDSN * sizeof(float2);  // 129512 B

    const bool use_lut = ws_size >= (size_t)NFFT * sizeof(float2);
    float2* cross = use_lut ? (float2*)d_ws : nullptr;
    if (use_lut) {
        hipLaunchKernelGGL(fill_cross_lut, dim3((NFFT + 255) / 256), dim3(256), 0, stream,
                           cross);
    }

    hipFuncSetAttribute((const void*)mcb_fft_conv_kernel,
                        hipFuncAttributeMaxDynamicSharedMemorySize,
                        (int)lds_bytes);

    hipLaunchKernelGGL(mcb_fft_conv_kernel, dim3(B), dim3(TPB), lds_bytes, stream,
                       img, seq, hvec, svec, out, cross);
}

// Round 4
// 418.486 us; speedup vs baseline: 2.0469x; 1.0133x over previous
//
#include <hip/hip_runtime.h>
#include <math.h>

#define NFFT  16000   // = 128 * 125
#define NCCOL 125     // radix-5 axis (contiguous)
#define DFEAT 2048
#define TPB   1024
#define R2OFF 16000   // LDS offset: 64-entry w_128^j LUT (forward sign)
#define R5OFF 16064   // LDS offset: 125-entry w_125^k LUT (forward sign)
#define LDSN  16189   // total float2 elements in LDS

__device__ __forceinline__ float2 cmul(float2 a, float2 b) {
    return make_float2(a.x*b.x - a.y*b.y, a.x*b.y + a.y*b.x);
}
__device__ __forceinline__ float2 cmulc(float2 a, float2 b) {   // a * conj(b)
    return make_float2(a.x*b.x + a.y*b.y, a.y*b.x - a.x*b.y);
}
__device__ __forceinline__ float2 cadd(float2 a, float2 b){ return make_float2(a.x+b.x, a.y+b.y); }
__device__ __forceinline__ float2 csub(float2 a, float2 b){ return make_float2(a.x-b.x, a.y-b.y); }
// e^{i*pi*a}
__device__ __forceinline__ float2 eipi(float a) {
    float s, c;
    sincospif(a, &s, &c);
    return make_float2(c, s);
}

#define C1f 0.30901699437494742f
#define C2f (-0.80901699437494745f)
#define S1f 0.95105651629515357f
#define S2f 0.58778525229247314f

// forward (DIF) radix-5 butterfly, in place, no twiddles
__device__ __forceinline__ void bfly5_fwd(float2& e0, float2& e1, float2& e2,
                                          float2& e3, float2& e4) {
    float2 t1 = cadd(e1, e4), t2 = cadd(e2, e3);
    float2 t3 = csub(e1, e4), t4 = csub(e2, e3);
    float2 f0 = make_float2(e0.x + t1.x + t2.x, e0.y + t1.y + t2.y);
    float2 m1 = make_float2(e0.x + C1f*t1.x + C2f*t2.x, e0.y + C1f*t1.y + C2f*t2.y);
    float2 m2 = make_float2(e0.x + C2f*t1.x + C1f*t2.x, e0.y + C2f*t1.y + C1f*t2.y);
    float2 v1 = make_float2(S1f*t3.x + S2f*t4.x, S1f*t3.y + S2f*t4.y);
    float2 v2 = make_float2(S2f*t3.x - S1f*t4.x, S2f*t3.y - S1f*t4.y);
    e0 = f0;
    e1 = make_float2(m1.x + v1.y, m1.y - v1.x);   // m1 - i v1
    e4 = make_float2(m1.x - v1.y, m1.y + v1.x);   // m1 + i v1
    e2 = make_float2(m2.x + v2.y, m2.y - v2.x);   // m2 - i v2
    e3 = make_float2(m2.x - v2.y, m2.y + v2.x);   // m2 + i v2
}
// inverse (DIT) radix-5 butterfly, in place, no twiddles
__device__ __forceinline__ void bfly5_inv(float2& e0, float2& e1, float2& e2,
                                          float2& e3, float2& e4) {
    float2 t1 = cadd(e1, e4), t2 = cadd(e2, e3);
    float2 t3 = csub(e1, e4), t4 = csub(e2, e3);
    float2 f0 = make_float2(e0.x + t1.x + t2.x, e0.y + t1.y + t2.y);
    float2 m1 = make_float2(e0.x + C1f*t1.x + C2f*t2.x, e0.y + C1f*t1.y + C2f*t2.y);
    float2 m2 = make_float2(e0.x + C2f*t1.x + C1f*t2.x, e0.y + C2f*t1.y + C1f*t2.y);
    float2 v1 = make_float2(S1f*t3.x + S2f*t4.x, S1f*t3.y + S2f*t4.y);
    float2 v2 = make_float2(S2f*t3.x - S1f*t4.x, S2f*t3.y - S1f*t4.y);
    e0 = f0;
    e1 = make_float2(m1.x - v1.y, m1.y + v1.x);   // m1 + i v1
    e4 = make_float2(m1.x + v1.y, m1.y - v1.x);   // m1 - i v1
    e2 = make_float2(m2.x - v2.y, m2.y + v2.x);   // m2 + i v2
    e3 = make_float2(m2.x + v2.y, m2.y - v2.x);   // m2 - i v2
}

// Cross-twiddle LUT: Wc[p] = exp(-2*pi*i * c * brev7(r) / N), p = r*125 + c
__global__ void fill_cross_lut(float2* __restrict__ ws) {
    int p = blockIdx.x * 256 + threadIdx.x;
    if (p < NFFT) {
        int r  = p / NCCOL;
        int c  = p - r * NCCOL;
        int k1 = __brev((unsigned)r) >> 25;
        ws[p]  = eipi((float)(c * k1) * (-2.0f / (float)NFFT));
    }
}

// One block per batch row. LDS holds z[16000] complex + twiddle LUTs.
// Forward: z = sk_img + i*sk_seq ; Z = FFT(z) (DIF four-step 128x125,
//          radix-8 + radix-16(+cross) on the 128 axis, radix-25 on 125)
// FSQ: forward L=5 + spectrum square + inverse L=5, one fused contiguous pass
// Inverse: mirror DIT, natural-order output; out = Im(w)/(2N) fused into last pass.
__global__ void __launch_bounds__(TPB, 1)
mcb_fft_conv_kernel(const float* __restrict__ img, const float* __restrict__ seq,
                    const int* __restrict__ hvec, const float* __restrict__ svec,
                    float* __restrict__ out, const float2* __restrict__ cross)
{
    extern __shared__ float2 buf[];
    const int tid = threadIdx.x;
    const int b   = blockIdx.x;

    #define W2L(k) buf[R2OFF + (k)]
    #define R5L(k) buf[R5OFF + (k)]

    auto CW = [&](int p) -> float2 {
        if (cross) return cross[p];
        int r = p / NCCOL, c = p - r * NCCOL;
        int k1 = __brev((unsigned)r) >> 25;
        return eipi((float)(c * k1) * (-2.0f / (float)NFFT));
    };

    // ---- zero (vectorized) + build LDS twiddle LUTs
    {
        float4* b4 = (float4*)buf;                 // 16000 float2 = 8000 float4
        for (int p = tid; p < NFFT / 2; p += TPB) b4[p] = make_float4(0.f, 0.f, 0.f, 0.f);
    }
    if (tid < 64) {
        W2L(tid) = eipi(-(float)tid * (1.0f / 64.0f));        // w_128^j
    } else if (tid < 64 + 125) {
        int k = tid - 64;
        R5L(k) = eipi((float)k * (-2.0f / 125.0f));           // w_125^k
    }
    __syncthreads();

    // ---- count-sketch scatter (img -> re, seq -> im)
    {
        const float* irow = img + (size_t)b * DFEAT;
        const float* qrow = seq + (size_t)b * DFEAT;
        for (int j = tid; j < DFEAT; j += TPB) {
            float sj = svec[j];
            int   hj = hvec[j];
            atomicAdd(&buf[hj].x, irow[j] * sj);
            atomicAdd(&buf[hj].y, qrow[j] * sj);
        }
    }
    __syncthreads();

    // ======== F1: forward radix-8, stages ls=6,5,4  (rows j + 16t) ========
    for (int idx = tid; idx < 16 * NCCOL; idx += TPB) {
        const int j = idx / NCCOL;          // 0..15
        const int c = idx - j * NCCOL;
        const int base = j * NCCOL + c;
        float2 x[8];
        #pragma unroll
        for (int t = 0; t < 8; ++t) x[t] = buf[base + 2000 * t];
        // ls=6 (dist 4): twiddle w128^{j+16t}
        #pragma unroll
        for (int t = 0; t < 4; ++t) {
            float2 u = x[t], v = x[t+4];
            x[t]   = cadd(u, v);
            x[t+4] = cmul(csub(u, v), W2L(j + 16*t));
        }
        // ls=5 (dist 2): twiddle w128^{2(j+16t)}, t=0,1
        #pragma unroll
        for (int q = 0; q < 8; q += 4)
            #pragma unroll
            for (int t = 0; t < 2; ++t) {
                float2 u = x[q+t], v = x[q+t+2];
                x[q+t]   = cadd(u, v);
                x[q+t+2] = cmul(csub(u, v), W2L(2*(j + 16*t)));
            }
        // ls=4 (dist 1): twiddle w128^{4j}
        {
            float2 w = W2L(4*j);
            #pragma unroll
            for (int q = 0; q < 8; q += 2) {
                float2 u = x[q], v = x[q+1];
                x[q]   = cadd(u, v);
                x[q+1] = cmul(csub(u, v), w);
            }
        }
        #pragma unroll
        for (int t = 0; t < 8; ++t) buf[base + 2000 * t] = x[t];
    }
    __syncthreads();

    // ======== F2: forward radix-16, stages ls=3..0 + cross twiddle (rows 16g+t) ====
    for (int idx = tid; idx < 8 * NCCOL; idx += TPB) {
        const int g = idx / NCCOL;          // 0..7
        const int c = idx - g * NCCOL;
        const int base = 2000 * g + c;
        float2 x[16];
        #pragma unroll
        for (int t = 0; t < 16; ++t) x[t] = buf[base + 125 * t];
        // ls=3 (dist 8): twiddle w128^{8t}
        #pragma unroll
        for (int t = 0; t < 8; ++t) {
            float2 u = x[t], v = x[t+8];
            x[t]   = cadd(u, v);
            x[t+8] = cmul(csub(u, v), W2L(8*t));
        }
        // ls=2 (dist 4): twiddle w128^{16t}, t=0..3
        #pragma unroll
        for (int q = 0; q < 16; q += 8)
            #pragma unroll
            for (int t = 0; t < 4; ++t) {
                float2 u = x[q+t], v = x[q+t+4];
                x[q+t]   = cadd(u, v);
                x[q+t+4] = cmul(csub(u, v), W2L(16*t));
            }
        // ls=1 (dist 2): twiddle w128^{32t}, t=0,1
        #pragma unroll
        for (int q = 0; q < 16; q += 4)
            #pragma unroll
            for (int t = 0; t < 2; ++t) {
                float2 u = x[q+t], v = x[q+t+2];
                x[q+t]   = cadd(u, v);
                x[q+t+2] = cmul(csub(u, v), W2L(32*t));
            }
        // ls=0 (dist 1): twiddle 1
        #pragma unroll
        for (int q = 0; q < 16; q += 2) {
            float2 u = x[q], v = x[q+1];
            x[q]   = cadd(u, v);
            x[q+1] = csub(u, v);
        }
        // cross twiddle (element at row 16g+t has flat index base + 125t)
        #pragma unroll
        for (int t = 0; t < 16; ++t)
            buf[base + 125 * t] = cmul(x[t], CW(base + 125 * t));
    }
    __syncthreads();

    // ======== F3: forward radix-25 (stages L=125, L=25) along columns ========
    for (int idx = tid; idx < 128 * 5; idx += TPB) {
        const int r  = idx / 5;
        const int j2 = idx - r * 5;
        const int base = r * NCCOL + j2;
        float2 x[25];
        #pragma unroll
        for (int q = 0; q < 25; ++q) x[q] = buf[base + 5 * q];
        // L=125: butterfly over t5 for each p, twiddle w125^{t*(j2+5p)}
        #pragma unroll
        for (int p = 0; p < 5; ++p) {
            bfly5_fwd(x[p], x[p+5], x[p+10], x[p+15], x[p+20]);
            const int jw = j2 + 5*p;
            x[p+5]  = cmul(x[p+5],  R5L(jw));
            x[p+10] = cmul(x[p+10], R5L(2*jw));
            x[p+15] = cmul(x[p+15], R5L(3*jw));
            x[p+20] = cmul(x[p+20], R5L(4*jw));
        }
        // L=25: butterfly over p for each t5, twiddle w25^{t*j2} = w125^{5t*j2}
        #pragma unroll
        for (int t5 = 0; t5 < 5; ++t5) {
            bfly5_fwd(x[5*t5], x[1+5*t5], x[2+5*t5], x[3+5*t5], x[4+5*t5]);
            x[1+5*t5] = cmul(x[1+5*t5], R5L(5*j2));
            x[2+5*t5] = cmul(x[2+5*t5], R5L(10*j2));
            x[3+5*t5] = cmul(x[3+5*t5], R5L(15*j2));
            x[4+5*t5] = cmul(x[4+5*t5], R5L(20*j2));
        }
        #pragma unroll
        for (int q = 0; q < 25; ++q) buf[base + 5 * q] = x[q];
    }
    __syncthreads();

    // ======== FSQ: forward L=5 + spectrum square + inverse L=5 (fused) ========
    // Both stages operate on the same contiguous groups {r*125+5q .. +4}.
    for (int idx = tid; idx < 128 * 25; idx += TPB) {
        const int r = idx / 25;
        const int q = idx - r * 25;
        const int base = r * NCCOL + 5 * q;
        float2 g0 = buf[base], g1 = buf[base+1], g2 = buf[base+2],
               g3 = buf[base+3], g4 = buf[base+4];
        bfly5_fwd(g0, g1, g2, g3, g4);                      // forward stage L=5
        g0 = make_float2(g0.x*g0.x - g0.y*g0.y, 2.f*g0.x*g0.y);   // Z^2
        g1 = make_float2(g1.x*g1.x - g1.y*g1.y, 2.f*g1.x*g1.y);
        g2 = make_float2(g2.x*g2.x - g2.y*g2.y, 2.f*g2.x*g2.y);
        g3 = make_float2(g3.x*g3.x - g3.y*g3.y, 2.f*g3.x*g3.y);
        g4 = make_float2(g4.x*g4.x - g4.y*g4.y, 2.f*g4.x*g4.y);
        bfly5_inv(g0, g1, g2, g3, g4);                      // inverse stage L=5
        buf[base] = g0; buf[base+1] = g1; buf[base+2] = g2;
        buf[base+3] = g3; buf[base+4] = g4;
    }
    __syncthreads();

    // ======== I2: inverse radix-25 (stages L=25, L=125) ========
    for (int idx = tid; idx < 128 * 5; idx += TPB) {
        const int r  = idx / 5;
        const int j2 = idx - r * 5;
        const int base = r * NCCOL + j2;
        float2 x[25];
        #pragma unroll
        for (int q = 0; q < 25; ++q) x[q] = buf[base + 5 * q];
        // L=25 DIT: conj twiddle then inverse butterfly over p (per t5)
        #pragma unroll
        for (int t5 = 0; t5 < 5; ++t5) {
            x[1+5*t5] = cmulc(x[1+5*t5], R5L(5*j2));
            x[2+5*t5] = cmulc(x[2+5*t5], R5L(10*j2));
            x[3+5*t5] = cmulc(x[3+5*t5], R5L(15*j2));
            x[4+5*t5] = cmulc(x[4+5*t5], R5L(20*j2));
            bfly5_inv(x[5*t5], x[1+5*t5], x[2+5*t5], x[3+5*t5], x[4+5*t5]);
        }
        // L=125 DIT: conj twiddle then inverse butterfly over t5 (per p)
        #pragma unroll
        for (int p = 0; p < 5; ++p) {
            const int jw = j2 + 5*p;
            x[p+5]  = cmulc(x[p+5],  R5L(jw));
            x[p+10] = cmulc(x[p+10], R5L(2*jw));
            x[p+15] = cmulc(x[p+15], R5L(3*jw));
            x[p+20] = cmulc(x[p+20], R5L(4*jw));
            bfly5_inv(x[p], x[p+5], x[p+10], x[p+15], x[p+20]);
        }
        #pragma unroll
        for (int q = 0; q < 25; ++q) buf[base + 5 * q] = x[q];
    }
    __syncthreads();

    // ======== I3: inverse radix-16: conj cross + stages ls=0..3 (rows 16g+t) ====
    for (int idx = tid; idx < 8 * NCCOL; idx += TPB) {
        const int g = idx / NCCOL;
        const int c = idx - g * NCCOL;
        const int base = 2000 * g + c;
        float2 x[16];
        #pragma unroll
        for (int t = 0; t < 16; ++t)
            x[t] = cmulc(buf[base + 125 * t], CW(base + 125 * t));
        // ls=0 (dist 1): twiddle 1
        #pragma unroll
        for (int q = 0; q < 16; q += 2) {
            float2 u = x[q], v = x[q+1];
            x[q]   = cadd(u, v);
            x[q+1] = csub(u, v);
        }
        // ls=1 (dist 2): conj w128^{32t}
        #pragma unroll
        for (int q = 0; q < 16; q += 4)
            #pragma unroll
            for (int t = 0; t < 2; ++t) {
                float2 u = x[q+t];
                float2 v = cmulc(x[q+t+2], W2L(32*t));
                x[q+t]   = cadd(u, v);
                x[q+t+2] = csub(u, v);
            }
        // ls=2 (dist 4): conj w128^{16t}
        #pragma unroll
        for (int q = 0; q < 16; q += 8)
            #pragma unroll
            for (int t = 0; t < 4; ++t) {
                float2 u = x[q+t];
                float2 v = cmulc(x[q+t+4], W2L(16*t));
                x[q+t]   = cadd(u, v);
                x[q+t+4] = csub(u, v);
            }
        // ls=3 (dist 8): conj w128^{8t}
        #pragma unroll
        for (int t = 0; t < 8; ++t) {
            float2 u = x[t];
            float2 v = cmulc(x[t+8], W2L(8*t));
            x[t]   = cadd(u, v);
            x[t+8] = csub(u, v);
        }
        #pragma unroll
        for (int t = 0; t < 16; ++t) buf[base + 125 * t] = x[t];
    }
    __syncthreads();

    // ======== I4: inverse radix-8, stages ls=4,5,6 + output write (rows j+16t) ====
    const float scale = 1.0f / (2.0f * (float)NFFT);
    float* orow = out + (size_t)b * NFFT;
    for (int idx = tid; idx < 16 * NCCOL; idx += TPB) {
        const int j = idx / NCCOL;
        const int c = idx - j * NCCOL;
        const int base = j * NCCOL + c;
        float2 x[8];
        #pragma unroll
        for (int t = 0; t < 8; ++t) x[t] = buf[base + 2000 * t];
        // ls=4 (dist 1): conj w128^{4j}
        {
            float2 w = W2L(4*j);
            #pragma unroll
            for (int q = 0; q < 8; q += 2) {
                float2 u = x[q];
                float2 v = cmulc(x[q+1], w);
                x[q]   = cadd(u, v);
                x[q+1] = csub(u, v);
            }
        }
        // ls=5 (dist 2): conj w128^{2(j+16t)}, t=0,1
        #pragma unroll
        for (int q = 0; q < 8; q += 4)
            #pragma unroll
            for (int t = 0; t < 2; ++t) {
                float2 u = x[q+t];
                float2 v = cmulc(x[q+t+2], W2L(2*(j + 16*t)));
                x[q+t]   = cadd(u, v);
                x[q+t+2] = csub(u, v);
            }
        // ls=6 (dist 4): conj w128^{j+16t}, t=0..3 — then emit Im*scale
        #pragma unroll
        for (int t = 0; t < 4; ++t) {
            float2 u = x[t];
            float2 v = cmulc(x[t+4], W2L(j + 16*t));
            orow[base + 2000 * t]       = (u.y + v.y) * scale;
            orow[base + 2000 * (t + 4)] = (u.y - v.y) * scale;
        }
    }
}

extern "C" void kernel_launch(void* const* d_in, const int* in_sizes, int n_in,
                              void* d_out, int out_size, void* d_ws, size_t ws_size,
                              hipStream_t stream)
{
    const float* img  = (const float*)d_in[0];
    const float* seq  = (const float*)d_in[1];
    const int*   hvec = (const int*)d_in[2];
    const float* svec = (const float*)d_in[3];
    float* out = (float*)d_out;

    const int B = in_sizes[0] / DFEAT;   // 2048
    const size_t lds_bytes = (size_t)LDSN * sizeof(float2);  // 129512 B

    const bool use_lut = ws_size >= (size_t)NFFT * sizeof(float2);
    float2* cross = use_lut ? (float2*)d_ws : nullptr;
    if (use_lut) {
        hipLaunchKernelGGL(fill_cross_lut, dim3((NFFT + 255) / 256), dim3(256), 0, stream,
                           cross);
    }

    hipFuncSetAttribute((const void*)mcb_fft_conv_kernel,
                        hipFuncAttributeMaxDynamicSharedMemorySize,
                        (int)lds_bytes);

    hipLaunchKernelGGL(mcb_fft_conv_kernel, dim3(B), dim3(TPB), lds_bytes, stream,
                       img, seq, hvec, svec, out, cross);
}